// Round 1
// 582.558 us; speedup vs baseline: 1.0039x; 1.0039x over previous
//
#include <hip/hip_runtime.h>
#include <stdint.h>

// Correlation_29609504538974: 6-level spatial correlation, patch 3x3 + leaky_relu(corr/C).
// out_l[b, t, y, x] = leaky( (1/C) * sum_c f1[b,c,y,x] * f2[b,c,y+di,x+dj] ),
//   t=(di+1)*3+(dj+1); f1 = x_l, f2 = x_pre_l. Zero pad outside.
//
// R5: R4 was throttled by device-scope atomics (WRITE_SIZE 241MB vs 3MB true output;
// 15.3M memory-side RMWs ~48G/s; loads queued behind them at 0.66 TB/s read BW).
// New structure: ONE kernel, NO atomics, no zero/fin passes.
//   - block (256 thr = 4 waves) owns one pixel tile x ALL channels.
//   - waves split channels 4-way, accumulate 9 taps in registers,
//     LDS tree-reduce (4x9KB), fused scale+leaky, direct final stores.
//   - tile = 256px (4 px/lane, float4) except L1/L5 = 128px (2 px/lane, float2)
//     so per-block bytes are balanced (L1 has C=1024). L1 blocks dispatched first (LPT).
//   - dj=+-1 taps via clamped edge dword loads (no shuffles in the load->FMA path);
//     clamp garbage only ever lands in taps masked at store time.
// Grid: 128(L1)+256(L0)+16(L2)+4(L3)+1(L4)+1(L5) = 406 blocks.

struct Lv {
  const float* f1;
  const float* f2;
  int C, ss;       // channels, log2(S)
  int csize;       // C/4 channels per wave
  int pxs;         // log2(px per lane): 2 -> float4 path, 1 -> float2 path
  uint32_t npix;   // B*S*S
  uint32_t blk_end;  // cumulative block count in GRID order
  uint32_t out_off;
  float invC;
};
struct P { Lv lv[6]; };

__global__ __launch_bounds__(256) void corr_all(P p, float* __restrict__ out) {
  __shared__ float red[4][9 * 256];  // 36 KB

  const uint32_t bid = blockIdx.x;
  int l = 0;
#pragma unroll
  for (int i = 0; i < 5; ++i) l += (bid >= p.lv[i].blk_end) ? 1 : 0;
  const Lv L = p.lv[l];
  const uint32_t tile = bid - (l ? p.lv[l - 1].blk_end : 0u);

  const int w = (int)(threadIdx.x >> 6);
  const int lane = (int)(threadIdx.x & 63u);
  const int ss = L.ss;
  const int S = 1 << ss;
  const int S2 = 1 << (2 * ss);
  const int pxs = L.pxs;
  const int PXL = 1 << pxs;
  const int TP = 64 << pxs;

  uint32_t pix0 = tile * (uint32_t)TP + ((uint32_t)lane << pxs);
  if (pix0 >= L.npix) pix0 = L.npix - (uint32_t)PXL;  // L5 tail lanes: compute garbage, stores masked
  const uint32_t b = pix0 >> (2 * ss);
  const uint32_t yx = pix0 & (uint32_t)(S2 - 1);
  const int y = (int)(yx >> ss);
  const int x0 = (int)(yx & (uint32_t)(S - 1));

  const size_t pbase = ((size_t)(b * (uint32_t)L.C + (uint32_t)(w * L.csize))) << (2 * ss);
  const float* __restrict__ f1p = L.f1 + pbase + yx;
  const float* __restrict__ f2b = L.f2 + pbase;

  int ro[3];
#pragma unroll
  for (int r = 0; r < 3; ++r) {
    int yy = y + r - 1;
    yy = yy < 0 ? 0 : (yy > S - 1 ? S - 1 : yy);  // clamped; garbage taps masked at store
    ro[r] = yy * S + x0;
  }
  const int cl = (x0 > 0) ? -1 : 0;              // left edge elem (garbage iff x0==0 -> masked)
  const int cr = (x0 + PXL < S) ? PXL : PXL - 1; // right edge elem (garbage iff at row end -> masked)

  if (pxs == 2) {
    // ---- 4 px / lane (float4) ----
    float acc[3][3][4];
#pragma unroll
    for (int r = 0; r < 3; ++r)
#pragma unroll
      for (int d = 0; d < 3; ++d)
#pragma unroll
        for (int e = 0; e < 4; ++e) acc[r][d][e] = 0.f;

    const int n = L.csize;
#pragma unroll 4
    for (int j = 0; j < n; ++j) {
      const float4 a = *(const float4*)f1p;
      const float4 v0 = *(const float4*)(f2b + ro[0]);
      const float l0 = f2b[ro[0] + cl];
      const float r0 = f2b[ro[0] + cr];
      const float4 v1 = *(const float4*)(f2b + ro[1]);
      const float l1 = f2b[ro[1] + cl];
      const float r1 = f2b[ro[1] + cr];
      const float4 v2 = *(const float4*)(f2b + ro[2]);
      const float l2 = f2b[ro[2] + cl];
      const float r2 = f2b[ro[2] + cr];
      f1p += S2;
      f2b += S2;
      const float av[4] = {a.x, a.y, a.z, a.w};
      const float vv[3][4] = {{v0.x, v0.y, v0.z, v0.w},
                              {v1.x, v1.y, v1.z, v1.w},
                              {v2.x, v2.y, v2.z, v2.w}};
      const float el[3] = {l0, l1, l2};
      const float er[3] = {r0, r1, r2};
#pragma unroll
      for (int r = 0; r < 3; ++r) {
        const float tm[4] = {el[r], vv[r][0], vv[r][1], vv[r][2]};
        const float tp[4] = {vv[r][1], vv[r][2], vv[r][3], er[r]};
#pragma unroll
        for (int e = 0; e < 4; ++e) {
          acc[r][0][e] = fmaf(av[e], tm[e], acc[r][0][e]);
          acc[r][1][e] = fmaf(av[e], vv[r][e], acc[r][1][e]);
          acc[r][2][e] = fmaf(av[e], tp[e], acc[r][2][e]);
        }
      }
    }
#pragma unroll
    for (int r = 0; r < 3; ++r)
#pragma unroll
      for (int d = 0; d < 3; ++d) {
        const int t = r * 3 + d;
        *(float4*)&red[w][t * 256 + lane * 4] =
            make_float4(acc[r][d][0], acc[r][d][1], acc[r][d][2], acc[r][d][3]);
      }
  } else {
    // ---- 2 px / lane (float2) ----
    float acc[3][3][2];
#pragma unroll
    for (int r = 0; r < 3; ++r)
#pragma unroll
      for (int d = 0; d < 3; ++d)
#pragma unroll
        for (int e = 0; e < 2; ++e) acc[r][d][e] = 0.f;

    const int n = L.csize;
#pragma unroll 4
    for (int j = 0; j < n; ++j) {
      const float2 a = *(const float2*)f1p;
      const float2 v0 = *(const float2*)(f2b + ro[0]);
      const float l0 = f2b[ro[0] + cl];
      const float r0 = f2b[ro[0] + cr];
      const float2 v1 = *(const float2*)(f2b + ro[1]);
      const float l1 = f2b[ro[1] + cl];
      const float r1 = f2b[ro[1] + cr];
      const float2 v2 = *(const float2*)(f2b + ro[2]);
      const float l2 = f2b[ro[2] + cl];
      const float r2 = f2b[ro[2] + cr];
      f1p += S2;
      f2b += S2;
      const float av[2] = {a.x, a.y};
      const float vv[3][2] = {{v0.x, v0.y}, {v1.x, v1.y}, {v2.x, v2.y}};
      const float el[3] = {l0, l1, l2};
      const float er[3] = {r0, r1, r2};
#pragma unroll
      for (int r = 0; r < 3; ++r) {
        const float tm[2] = {el[r], vv[r][0]};
        const float tp[2] = {vv[r][1], er[r]};
#pragma unroll
        for (int e = 0; e < 2; ++e) {
          acc[r][0][e] = fmaf(av[e], tm[e], acc[r][0][e]);
          acc[r][1][e] = fmaf(av[e], vv[r][e], acc[r][1][e]);
          acc[r][2][e] = fmaf(av[e], tp[e], acc[r][2][e]);
        }
      }
    }
#pragma unroll
    for (int r = 0; r < 3; ++r)
#pragma unroll
      for (int d = 0; d < 3; ++d) {
        const int t = r * 3 + d;
        *(float2*)&red[w][t * 128 + lane * 2] = make_float2(acc[r][d][0], acc[r][d][1]);
      }
  }

  __syncthreads();

  // LDS reduce across the 4 channel-split waves + fused scale/leaky + final store.
  const int tot = 9 * TP;
  for (int idx = (int)threadIdx.x; idx < tot; idx += 256) {
    const float s = red[0][idx] + red[1][idx] + red[2][idx] + red[3][idx];
    const int t = idx >> (6 + pxs);
    const int pl = idx & (TP - 1);
    const uint32_t px = tile * (uint32_t)TP + (uint32_t)pl;
    if (px < L.npix) {
      const uint32_t bb = px >> (2 * ss);
      const uint32_t pyx = px & (uint32_t)(S2 - 1);
      const int py = (int)(pyx >> ss);
      const int pxx = (int)(pyx & (uint32_t)(S - 1));
      const int di = t / 3 - 1;
      const int dj = t - (t / 3) * 3 - 1;
      const int qy = py + di;
      const int qx = pxx + dj;
      float v = 0.f;
      if ((qy >= 0) & (qy < S) & (qx >= 0) & (qx < S)) {
        v = s * L.invC;
        v = v >= 0.f ? v : 0.01f * v;
      }
      out[(size_t)L.out_off + (((size_t)(bb * 9u + (uint32_t)t)) << (2 * ss)) + pyx] = v;
    }
  }
}

extern "C" void kernel_launch(void* const* d_in, const int* in_sizes, int n_in,
                              void* d_out, int out_size, void* d_ws, size_t ws_size,
                              hipStream_t stream) {
  static const int CH[6] = {512, 1024, 512, 256, 256, 256};
  static const int LG[6] = {6, 5, 4, 3, 2, 1};
  static const int PXS[6] = {2, 1, 2, 2, 2, 1};     // L1 & L5 use 2 px/lane
  static const int PERM[6] = {1, 0, 2, 3, 4, 5};    // longest blocks (L1) first

  // setup_inputs() dict order is interleaved: d_in[2i]=x_pre_i, d_in[2i+1]=x_i.
  const bool interleaved = (n_in >= 2) && (in_sizes[0] == in_sizes[1]);

  uint32_t ooff[6];
  uint32_t oacc = 0;
  for (int i = 0; i < 6; ++i) {
    ooff[i] = oacc;
    const int S = 1 << LG[i];
    oacc += 9u * 16u * (uint32_t)(S * S);
  }

  P pv;
  uint32_t bend = 0;
  for (int k = 0; k < 6; ++k) {
    const int i = PERM[k];
    const int S = 1 << LG[i];
    const uint32_t npix = 16u * (uint32_t)(S * S);
    const int TP = 64 << PXS[i];
    const uint32_t tiles = (npix + (uint32_t)TP - 1u) / (uint32_t)TP;
    Lv& L = pv.lv[k];
    L.f1 = (const float*)d_in[interleaved ? (2 * i + 1) : (6 + i)];
    L.f2 = (const float*)d_in[interleaved ? (2 * i) : i];
    L.C = CH[i];
    L.ss = LG[i];
    L.csize = CH[i] / 4;
    L.pxs = PXS[i];
    L.npix = npix;
    bend += tiles;
    L.blk_end = bend;
    L.out_off = ooff[i];
    L.invC = 1.0f / (float)CH[i];
  }

  corr_all<<<bend, 256, 0, stream>>>(pv, (float*)d_out);
}

// Round 2
// 407.430 us; speedup vs baseline: 1.4353x; 1.4298x over previous
//
#include <hip/hip_runtime.h>
#include <stdint.h>

// Correlation_29609504538974: 6-level spatial correlation, patch 3x3 + leaky_relu(corr/C).
// out_l[b, t, y, x] = leaky( (1/C) * sum_c f1[b,c,y,x] * f2[b,c,y+di,x+dj] ),
//   t=(di+1)*3+(dj+1); f1 = x_l, f2 = x_pre_l. Zero pad outside.
//
// R6: R5 (single kernel, no atomics) was occupancy/latency-bound: 406 blocks on
// 256 CUs -> 16% occupancy, VALUBusy 5%, 775 GB/s (9.7% peak). Same structure,
// more parallelism:
//   - 512-thread blocks (8 waves), channels split 8-way across waves.
//   - pixel tile = 128 px (2 px/lane, float2) -> 683 blocks (2.67/CU),
//     LDS 36 KB (8x9x128 f32) allows 4 blocks/CU; __launch_bounds__(512,4)
//     caps VGPR at 128 -> 2 resident blocks/CU = 16 waves/CU (~50% occ).
//   - dj=+-1 taps via __shfl_up/down (R4-validated): shuffle garbage (row edges,
//     clamped tail lanes) only ever lands in taps masked at store time.
//     4 VMEM instrs per channel-iter (1 f1 + 3 f2 rows, all float2).
//   - LDS tree-reduce over 8 waves, fused scale+leaky, direct final stores.
// Grid order LPT: L1 (C=1024, heaviest blocks) first.

struct Lv {
  const float* f1;
  const float* f2;
  int C, ss;         // channels, log2(S)
  int csize;         // C/8 channels per wave
  uint32_t npix;     // B*S*S
  uint32_t blk_end;  // cumulative block count in GRID order
  uint32_t out_off;
  float invC;
};
struct P { Lv lv[6]; };

__global__ __launch_bounds__(512, 4) void corr_all(P p, float* __restrict__ out) {
  __shared__ float red[8][9 * 128];  // 36 KB

  const uint32_t bid = blockIdx.x;
  int l = 0;
#pragma unroll
  for (int i = 0; i < 5; ++i) l += (bid >= p.lv[i].blk_end) ? 1 : 0;
  const Lv L = p.lv[l];
  const uint32_t tile = bid - (l ? p.lv[l - 1].blk_end : 0u);

  const int w = (int)(threadIdx.x >> 6);
  const int lane = (int)(threadIdx.x & 63u);
  const int ss = L.ss;
  const int S = 1 << ss;
  const int S2 = 1 << (2 * ss);

  uint32_t pix0 = tile * 128u + ((uint32_t)lane << 1);
  if (pix0 >= L.npix) pix0 = L.npix - 2u;  // L5 tail lanes: compute garbage, stores masked
  const uint32_t b = pix0 >> (2 * ss);
  const uint32_t yx = pix0 & (uint32_t)(S2 - 1);
  const int y = (int)(yx >> ss);
  const int x0 = (int)(yx & (uint32_t)(S - 1));  // even

  const size_t pbase = ((size_t)(b * (uint32_t)L.C + (uint32_t)(w * L.csize))) << (2 * ss);
  const float* __restrict__ f1p = L.f1 + pbase + yx;
  const float* __restrict__ f2b = L.f2 + pbase;

  int ro[3];
#pragma unroll
  for (int r = 0; r < 3; ++r) {
    int yy = y + r - 1;
    yy = yy < 0 ? 0 : (yy > S - 1 ? S - 1 : yy);  // clamped; garbage taps masked at store
    ro[r] = yy * S + x0;
  }

  float acc[3][3][2];
#pragma unroll
  for (int r = 0; r < 3; ++r)
#pragma unroll
    for (int d = 0; d < 3; ++d)
#pragma unroll
      for (int e = 0; e < 2; ++e) acc[r][d][e] = 0.f;

  const int n = L.csize;
#pragma unroll 4
  for (int j = 0; j < n; ++j) {
    const float2 a = *(const float2*)f1p;
    const float2 v0 = *(const float2*)(f2b + ro[0]);
    const float2 v1 = *(const float2*)(f2b + ro[1]);
    const float2 v2 = *(const float2*)(f2b + ro[2]);
    f1p += S2;
    f2b += S2;
    const float2 vv[3] = {v0, v1, v2};
#pragma unroll
    for (int r = 0; r < 3; ++r) {
      // prev lane's .y == f2[x0-1]; next lane's .x == f2[x0+2].
      // Row-crossing / tail-lane shuffle garbage only feeds store-masked taps.
      const float pw = __shfl_up(vv[r].y, 1);
      const float nx = __shfl_down(vv[r].x, 1);
      acc[r][0][0] = fmaf(a.x, pw, acc[r][0][0]);
      acc[r][0][1] = fmaf(a.y, vv[r].x, acc[r][0][1]);
      acc[r][1][0] = fmaf(a.x, vv[r].x, acc[r][1][0]);
      acc[r][1][1] = fmaf(a.y, vv[r].y, acc[r][1][1]);
      acc[r][2][0] = fmaf(a.x, vv[r].y, acc[r][2][0]);
      acc[r][2][1] = fmaf(a.y, nx, acc[r][2][1]);
    }
  }

#pragma unroll
  for (int r = 0; r < 3; ++r)
#pragma unroll
    for (int d = 0; d < 3; ++d) {
      const int t = r * 3 + d;
      *(float2*)&red[w][t * 128 + lane * 2] = make_float2(acc[r][d][0], acc[r][d][1]);
    }

  __syncthreads();

  // Reduce across the 8 channel-split waves + fused scale/leaky + final store.
  for (int idx = (int)threadIdx.x; idx < 9 * 128; idx += 512) {
    float s = 0.f;
#pragma unroll
    for (int ww = 0; ww < 8; ++ww) s += red[ww][idx];
    const int t = idx >> 7;
    const int pl = idx & 127;
    const uint32_t px = tile * 128u + (uint32_t)pl;
    if (px < L.npix) {
      const uint32_t bb = px >> (2 * ss);
      const uint32_t pyx = px & (uint32_t)(S2 - 1);
      const int py = (int)(pyx >> ss);
      const int pxx = (int)(pyx & (uint32_t)(S - 1));
      const int di = t / 3 - 1;
      const int dj = t - (t / 3) * 3 - 1;
      const int qy = py + di;
      const int qx = pxx + dj;
      float v = 0.f;
      if ((qy >= 0) & (qy < S) & (qx >= 0) & (qx < S)) {
        v = s * L.invC;
        v = v >= 0.f ? v : 0.01f * v;
      }
      out[(size_t)L.out_off + (((size_t)(bb * 9u + (uint32_t)t)) << (2 * ss)) + pyx] = v;
    }
  }
}

extern "C" void kernel_launch(void* const* d_in, const int* in_sizes, int n_in,
                              void* d_out, int out_size, void* d_ws, size_t ws_size,
                              hipStream_t stream) {
  static const int CH[6] = {512, 1024, 512, 256, 256, 256};
  static const int LG[6] = {6, 5, 4, 3, 2, 1};
  static const int PERM[6] = {1, 0, 2, 3, 4, 5};  // heaviest blocks (L1, C=1024) first

  // setup_inputs() dict order is interleaved: d_in[2i]=x_pre_i, d_in[2i+1]=x_i.
  const bool interleaved = (n_in >= 2) && (in_sizes[0] == in_sizes[1]);

  uint32_t ooff[6];
  uint32_t oacc = 0;
  for (int i = 0; i < 6; ++i) {
    ooff[i] = oacc;
    const int S = 1 << LG[i];
    oacc += 9u * 16u * (uint32_t)(S * S);
  }

  P pv;
  uint32_t bend = 0;
  for (int k = 0; k < 6; ++k) {
    const int i = PERM[k];
    const int S = 1 << LG[i];
    const uint32_t npix = 16u * (uint32_t)(S * S);
    const uint32_t tiles = (npix + 127u) / 128u;
    Lv& L = pv.lv[k];
    L.f1 = (const float*)d_in[interleaved ? (2 * i + 1) : (6 + i)];
    L.f2 = (const float*)d_in[interleaved ? (2 * i) : i];
    L.C = CH[i];
    L.ss = LG[i];
    L.csize = CH[i] / 8;
    L.npix = npix;
    bend += tiles;
    L.blk_end = bend;
    L.out_off = ooff[i];
    L.invC = 1.0f / (float)CH[i];
  }

  corr_all<<<bend, 512, 0, stream>>>(pv, (float*)d_out);
}

// Round 3
// 399.912 us; speedup vs baseline: 1.4623x; 1.0188x over previous
//
#include <hip/hip_runtime.h>
#include <stdint.h>

// Correlation_29609504538974: 6-level spatial correlation, patch 3x3 + leaky_relu(corr/C).
// out_l[b, t, y, x] = leaky( (1/C) * sum_c f1[b,c,y,x] * f2[b,c,y+di,x+dj] ),
//   t=(di+1)*3+(dj+1); f1 = x_l, f2 = x_pre_l. Zero pad outside.
//
// R7: R6 was doubly capped at 50% occupancy: grid 683 blocks (2.67/CU) AND
// ~112 real VGPRs (VGPR_Count=28 is granule-of-4) -> 4 waves/SIMD -> 2 blocks/CU.
// Latency-bound at 2.9 B/cy/CU (VALUBusy 9.8%, HBM 22%, L2 ~15%).
// Two coupled changes, same verified compute core:
//   1. Channel-chunked partials: L0 x2, L1 x4, L2 x2 chunks -> 1611 uniform blocks
//      (every wave exactly 32 iters). Partials to d_ws (7.4 MB, no atomics);
//      corr_fin sums <=4 chunks + mask + scale + leaky (~8 us). Fallback to
//      chunk=1 (raw sums into out, fin in-place) if ws too small.
//   2. Explicit depth-2 software pipeline (two named iter buffers) instead of
//      unroll-4: ~56 VGPRs -> 8 waves/SIMD; with LDS 36 KB -> 4 blocks/CU = 100%.
//      8 loads in flight/wave x 32 waves = 128 KB/CU outstanding >> 9 KB needed.

struct Lv {
  const float* f1;
  const float* f2;
  float* dst;        // partial base (ws region, or out region in fallback)
  int C, ss, csize;  // channels, log2(S), channels per wave
  uint32_t tiles;    // pixel tiles (npix/128)
  uint32_t npix;     // B*S*S
  uint32_t blk_end;  // cumulative block count
};
struct P { Lv lv[6]; };

struct Fv {
  const float* src;
  uint32_t end;      // cumulative out element end
  uint32_t cstride;  // 9*npix (chunk stride == level element count)
  uint32_t nchunk;
  int ss;
  float invC;
};
struct PF { Fv f[6]; uint32_t total; };

#define LOADIT(A, R0, R1, R2)                 \
  do {                                        \
    (A) = *(const float2*)f1p;                \
    (R0) = *(const float2*)(f2b + ro0);       \
    (R1) = *(const float2*)(f2b + ro1);       \
    (R2) = *(const float2*)(f2b + ro2);       \
    f1p += S2;                                \
    f2b += S2;                                \
  } while (0)

// prev lane's .y == f2[x-1]; next lane's .x == f2[x+2]. Row-crossing / tail-lane
// shuffle garbage only ever feeds taps masked in corr_fin (R4/R6-validated).
#define FMAROW(A, R, r)                                   \
  do {                                                    \
    const float pw = __shfl_up((R).y, 1);                 \
    const float nx = __shfl_down((R).x, 1);               \
    acc[r][0][0] = fmaf((A).x, pw, acc[r][0][0]);         \
    acc[r][0][1] = fmaf((A).y, (R).x, acc[r][0][1]);      \
    acc[r][1][0] = fmaf((A).x, (R).x, acc[r][1][0]);      \
    acc[r][1][1] = fmaf((A).y, (R).y, acc[r][1][1]);      \
    acc[r][2][0] = fmaf((A).x, (R).y, acc[r][2][0]);      \
    acc[r][2][1] = fmaf((A).y, nx, acc[r][2][1]);         \
  } while (0)

#define FMAIT(A, R0, R1, R2) \
  do {                       \
    FMAROW(A, R0, 0);        \
    FMAROW(A, R1, 1);        \
    FMAROW(A, R2, 2);        \
  } while (0)

__global__ __launch_bounds__(512, 6) void corr_part(P p) {
  __shared__ float red[8][9 * 128];  // 36 KB

  const uint32_t bid = blockIdx.x;
  int l = 0;
#pragma unroll
  for (int i = 0; i < 5; ++i) l += (bid >= p.lv[i].blk_end) ? 1 : 0;
  const Lv L = p.lv[l];
  const uint32_t local = bid - (l ? p.lv[l - 1].blk_end : 0u);
  const uint32_t chunk = local / L.tiles;   // chunk-major: tile-neighbors adjacent
  const uint32_t tile = local - chunk * L.tiles;

  const int w = (int)(threadIdx.x >> 6);
  const int lane = (int)(threadIdx.x & 63u);
  const int ss = L.ss;
  const int S = 1 << ss;
  const int S2 = 1 << (2 * ss);

  uint32_t pix0 = tile * 128u + ((uint32_t)lane << 1);
  if (pix0 >= L.npix) pix0 = L.npix - 2u;  // L5 tail lanes: garbage, stores masked
  const uint32_t b = pix0 >> (2 * ss);
  const uint32_t yx = pix0 & (uint32_t)(S2 - 1);
  const int y = (int)(yx >> ss);
  const int x0 = (int)(yx & (uint32_t)(S - 1));  // even
  (void)x0;

  const uint32_t c0 = chunk * (uint32_t)(8 * L.csize) + (uint32_t)(w * L.csize);
  const size_t pbase = ((size_t)(b * (uint32_t)L.C + c0)) << (2 * ss);
  const float* __restrict__ f1p = L.f1 + pbase + yx;
  const float* __restrict__ f2b = L.f2 + pbase;

  int yy0 = y - 1;
  yy0 = yy0 < 0 ? 0 : yy0;
  int yy2 = y + 1;
  yy2 = yy2 > S - 1 ? S - 1 : yy2;  // clamped; garbage taps masked in corr_fin
  const int xb = (int)(yx & (uint32_t)(S - 1));
  const int ro0 = yy0 * S + xb;
  const int ro1 = y * S + xb;
  const int ro2 = yy2 * S + xb;

  float acc[3][3][2];
#pragma unroll
  for (int r = 0; r < 3; ++r)
#pragma unroll
    for (int d = 0; d < 3; ++d)
#pragma unroll
      for (int e = 0; e < 2; ++e) acc[r][d][e] = 0.f;

  // Depth-2 software pipeline over n channel-iterations (n even, >= 2).
  const int n = L.csize;
  float2 a0, u0, v0, w0;
  float2 a1, u1, v1, w1;
  LOADIT(a0, u0, v0, w0);
#pragma unroll 1
  for (int j = 0; j + 2 < n; j += 2) {
    LOADIT(a1, u1, v1, w1);
    FMAIT(a0, u0, v0, w0);
    LOADIT(a0, u0, v0, w0);
    FMAIT(a1, u1, v1, w1);
  }
  LOADIT(a1, u1, v1, w1);
  FMAIT(a0, u0, v0, w0);
  FMAIT(a1, u1, v1, w1);

#pragma unroll
  for (int r = 0; r < 3; ++r)
#pragma unroll
    for (int d = 0; d < 3; ++d) {
      const int t = r * 3 + d;
      *(float2*)&red[w][t * 128 + lane * 2] = make_float2(acc[r][d][0], acc[r][d][1]);
    }

  __syncthreads();

  // Reduce across the 8 channel-split waves; store RAW partial sums (mask/scale
  // deferred to corr_fin).
  float* dbase = L.dst + (size_t)chunk * 9u * (size_t)L.npix;
  for (int idx = (int)threadIdx.x; idx < 9 * 128; idx += 512) {
    float s = 0.f;
#pragma unroll
    for (int ww = 0; ww < 8; ++ww) s += red[ww][idx];
    const int t = idx >> 7;
    const int pl = idx & 127;
    const uint32_t px = tile * 128u + (uint32_t)pl;
    if (px < L.npix) {
      const uint32_t bb = px >> (2 * ss);
      const uint32_t pyx = px & (uint32_t)(S2 - 1);
      dbase[(((size_t)(bb * 9u + (uint32_t)t)) << (2 * ss)) + pyx] = s;
    }
  }
}

__global__ __launch_bounds__(256) void corr_fin(PF p, float* __restrict__ out) {
  const uint32_t e = blockIdx.x * 256u + threadIdx.x;
  if (e >= p.total) return;
  int l = 0;
#pragma unroll
  for (int i = 0; i < 5; ++i) l += (e >= p.f[i].end) ? 1 : 0;
  const Fv F = p.f[l];
  const int ss = F.ss;
  const int S = 1 << ss;
  const int S2 = 1 << (2 * ss);
  const uint32_t local = e - (F.end - F.cstride);
  const uint32_t bt = local >> (2 * ss);
  const uint32_t yx = local & (uint32_t)(S2 - 1);
  const uint32_t t = bt % 9u;  // constant div -> magic mul
  const int y = (int)(yx >> ss);
  const int x = (int)(yx & (uint32_t)(S - 1));
  const int di = (int)t / 3 - 1;
  const int dj = (int)t % 3 - 1;
  const int qy = y + di;
  const int qx = x + dj;

  float s = 0.f;
  for (uint32_t k = 0; k < F.nchunk; ++k) s += F.src[(size_t)k * F.cstride + local];

  float v = 0.f;
  if ((qy >= 0) & (qy < S) & (qx >= 0) & (qx < S)) {
    v = s * F.invC;
    v = v >= 0.f ? v : 0.01f * v;
  }
  out[e] = v;
}

extern "C" void kernel_launch(void* const* d_in, const int* in_sizes, int n_in,
                              void* d_out, int out_size, void* d_ws, size_t ws_size,
                              hipStream_t stream) {
  static const int CH[6] = {512, 1024, 512, 256, 256, 256};
  static const int LG[6] = {6, 5, 4, 3, 2, 1};
  int NCK[6] = {2, 4, 2, 1, 1, 1};  // channel chunks -> every wave does 32 iters

  // setup_inputs() dict order is interleaved: d_in[2i]=x_pre_i, d_in[2i+1]=x_i.
  const bool interleaved = (n_in >= 2) && (in_sizes[0] == in_sizes[1]);

  uint32_t npixs[6], ooff[6], oacc = 0;
  for (int i = 0; i < 6; ++i) {
    npixs[i] = 16u << (2 * LG[i]);
    ooff[i] = oacc;
    oacc += 9u * npixs[i];
  }

  size_t wneed = 0;
  for (int i = 0; i < 6; ++i) wneed += (size_t)NCK[i] * 9u * npixs[i];
  wneed *= sizeof(float);
  const bool fb = (d_ws == nullptr) || (ws_size < wneed);
  if (fb)
    for (int i = 0; i < 6; ++i) NCK[i] = 1;  // raw sums straight into out; fin in-place

  P p;
  PF pf;
  float* ws = (float*)d_ws;
  float* out = (float*)d_out;
  uint32_t bend = 0;
  size_t woff = 0;
  for (int i = 0; i < 6; ++i) {
    const uint32_t tiles = (npixs[i] + 127u) / 128u;
    Lv& L = p.lv[i];
    L.f1 = (const float*)d_in[interleaved ? (2 * i + 1) : (6 + i)];
    L.f2 = (const float*)d_in[interleaved ? (2 * i) : i];
    L.dst = fb ? (out + ooff[i]) : (ws + woff);
    L.C = CH[i];
    L.ss = LG[i];
    L.csize = CH[i] / (8 * NCK[i]);
    L.tiles = tiles;
    L.npix = npixs[i];
    bend += tiles * (uint32_t)NCK[i];
    L.blk_end = bend;

    Fv& F = pf.f[i];
    F.src = L.dst;
    F.end = ooff[i] + 9u * npixs[i];
    F.cstride = 9u * npixs[i];
    F.nchunk = (uint32_t)NCK[i];
    F.ss = LG[i];
    F.invC = 1.0f / (float)CH[i];
    woff += (size_t)NCK[i] * 9u * npixs[i];
  }
  pf.total = oacc;

  corr_part<<<bend, 512, 0, stream>>>(p);
  corr_fin<<<(oacc + 255u) / 256u, 256, 0, stream>>>(pf, out);
}